// Round 6
// baseline (183.273 us; speedup 1.0000x reference)
//
#include <hip/hip_runtime.h>
#include <hip/hip_bf16.h>

#define EMB 10
#define DIN 36    // 2*EMB + 16 numeric
#define HID 128
#define BM  128   // rows per block

typedef __attribute__((ext_vector_type(8))) short short8;   // bf16x8 MFMA frag
typedef __attribute__((ext_vector_type(4))) float f32x4;    // fp32x4 acc frag

union U8 { unsigned u[4]; short8 v; };

__device__ __forceinline__ short bf16_hi(float v) {
  __hip_bfloat16 h = __float2bfloat16(v);
  return *reinterpret_cast<short*>(&h);
}
__device__ __forceinline__ float bf16_to_f(short s) {
  __hip_bfloat16 h = *reinterpret_cast<__hip_bfloat16*>(&s);
  return __bfloat162float(h);
}

// Truncation hi/lo split for a PAIR of floats, packed via v_perm_b32.
// hi = top-16-bits of fp32 (bf16 truncation, 1 instr for 2 elems);
// residual r = a - trunc(a) is EXACT (same exponent, Sterbenz);
// lo = truncation of r (error ~2^-16 |a| — same order as RNE split).
__device__ __forceinline__ void split_pair(float a, float b, unsigned &hi, unsigned &lo) {
  unsigned ua = __float_as_uint(a), ub = __float_as_uint(b);
  hi = __builtin_amdgcn_perm(ub, ua, 0x07060302u);   // [hi16(b) : hi16(a)]
  float ra = a - __uint_as_float(ua & 0xFFFF0000u);
  float rb = b - __uint_as_float(ub & 0xFFFF0000u);
  lo = __builtin_amdgcn_perm(__float_as_uint(rb), __float_as_uint(ra), 0x07060302u);
}

// Pack W1 (36x128) + b1 (as k=36 row, bias trick) into hi/lo bf16 B-fragments,
// K padded to 64. Layout: [term(2)][ct(8)][ks(2)][lane(64)][e(8)] bf16.
__global__ void prep_kernel(const float* __restrict__ W1, const float* __restrict__ b1,
                            short* __restrict__ Bpack) {
  int b = blockIdx.x;          // 32 blocks
  int term = b >> 4;           // 0 = hi, 1 = lo
  int ct   = (b >> 1) & 7;
  int ks   = b & 1;
  int l = threadIdx.x;         // 0..63
  int col = ct * 16 + (l & 15);
  int kb  = ks * 32 + (l >> 4) * 8;
  short8 o;
#pragma unroll
  for (int e = 0; e < 8; ++e) {
    int k = kb + e;
    float v = 0.0f;
    if (k < DIN)       v = W1[k * HID + col];
    else if (k == DIN) v = b1[col];
    short hb = bf16_hi(v);
    o[e] = (term == 0) ? hb : bf16_hi(v - bf16_to_f(hb));
  }
  *(short8*)(Bpack + (size_t)(((term * 8 + ct) * 2 + ks) * 64 + l) * 8) = o;
}

// no min-waves clause (R2 spill lesson). LDS 23.7 KB -> 6 blocks/CU cap.
__global__ __launch_bounds__(256)
void fused_kernel(const int* __restrict__ t1, const int* __restrict__ t2,
                  const float* __restrict__ numf,
                  const float* __restrict__ tab1, const float* __restrict__ tab2,
                  const short* __restrict__ Bpack,
                  const float* __restrict__ W2, const float* __restrict__ b2,
                  float* __restrict__ out, int N) {
  __shared__ float E1[134][11];     // 130 halo rows + 4 pad (clamp-free strips)
  __shared__ float E2[136][11];     // 134 halo rows + 2 pad
  __shared__ float Cs[BM][22];      // embeddings d0-19 only; stride 22 (8B align)
  __shared__ float W2s[HID];

  const int tid = threadIdx.x;
  const long base = (long)blockIdx.x * BM;
  const int wid = tid >> 6;
  const int l = tid & 63;
  const int arow = l & 15;
  const int kg = l >> 4;

  // ---- direct numeric loads for this thread's MFMA fragment slots ----
  // (numeric cols k=20..35 never touch LDS; loads issued before gathers)
  const long rg0 = base + (long)(wid * 2) * 16 + arow;
  const long rg1 = rg0 + 16;
  float4 qa0 = {0,0,0,0}, qa1 = {0,0,0,0}, qb0 = {0,0,0,0}, qb1 = {0,0,0,0};
  if (kg == 0) {                    // ks1 frag: n12-15
    if (rg0 < (long)N) qa0 = *(const float4*)(numf + rg0 * 16 + 12);
    if (rg1 < (long)N) qa1 = *(const float4*)(numf + rg1 * 16 + 12);
  } else if (kg == 2) {             // k20-23: n0-3
    if (rg0 < (long)N) qa0 = *(const float4*)(numf + rg0 * 16);
    if (rg1 < (long)N) qa1 = *(const float4*)(numf + rg1 * 16);
  } else if (kg == 3) {             // k24-31: n4-11
    if (rg0 < (long)N) { qa0 = *(const float4*)(numf + rg0 * 16 + 4);
                         qb0 = *(const float4*)(numf + rg0 * 16 + 8); }
    if (rg1 < (long)N) { qa1 = *(const float4*)(numf + rg1 * 16 + 4);
                         qb1 = *(const float4*)(numf + rg1 * 16 + 8); }
  }

  // E1 halo gather: threads 0..129; invalid rows ZERO-FILLED
  if (tid < 130) {
    long g = base - 1 + tid;
    if (g >= 0 && g < (long)N) {
      const float2* src = (const float2*)(tab1 + (long)t1[g] * EMB);
#pragma unroll
      for (int i = 0; i < 5; ++i) {
        float2 v = src[i];
        E1[tid][2 * i] = v.x; E1[tid][2 * i + 1] = v.y;
      }
    } else {
#pragma unroll
      for (int i = 0; i < EMB; ++i) E1[tid][i] = 0.0f;
    }
  }
  // E2 halo gather: threads 122..255 -> h 0..133
  {
    int h = tid - 122;
    if (h >= 0) {
      long g = base - 3 + h;
      if (g >= 0 && g < (long)N) {
        const float2* src = (const float2*)(tab2 + (long)t2[g] * EMB);
#pragma unroll
        for (int i = 0; i < 5; ++i) {
          float2 v = src[i];
          E2[h][2 * i] = v.x; E2[h][2 * i + 1] = v.y;
        }
      } else {
#pragma unroll
        for (int i = 0; i < EMB; ++i) E2[h][i] = 0.0f;
      }
    }
  }
  if (tid >= 128) W2s[tid - 128] = W2[tid - 128];
  __syncthreads();

  // ---- build phase: sliding-window tasks; uniform edge fast-path ----
  const bool edgeblk = (base == 0) || (base + BM + 3 > (long)N);
  if (tid < 120) {
    // E1 window-3: 12 groups x 11 rows x 10 dims (clamp-free, padded E1)
    int grp = tid / 10, d = tid - grp * 10;
    int r0 = grp * 11;
    float e[13];
#pragma unroll
    for (int i = 0; i < 13; ++i) e[i] = E1[r0 + i][d];
    if (!edgeblk) {
#pragma unroll
      for (int i = 0; i < 11; ++i) {
        int rr = r0 + i;
        if (rr < BM) Cs[rr][d] = (e[i] + e[i + 1] + e[i + 2]) * (1.0f / 3.0f);
      }
    } else {
#pragma unroll
      for (int i = 0; i < 11; ++i) {
        int rr = r0 + i;
        if (rr < BM) {
          long row = base + rr;
          long lo = row - 1; if (lo < 0) lo = 0;
          long hi = row + 2; if (hi > (long)N) hi = (long)N;
          long c = hi - lo;  if (c < 1) c = 1;
          Cs[rr][d] = (e[i] + e[i + 1] + e[i + 2]) / (float)c;
        }
      }
    }
  } else if (tid < 250) {
    // E2 window-7: 13 groups x 10 rows x 10 dims (clamp-free, padded E2)
    int u = tid - 120;
    int grp = u / 10, d = u - grp * 10;
    int r0 = grp * 10;
    float e[16];
#pragma unroll
    for (int i = 0; i < 16; ++i) e[i] = E2[r0 + i][d];
    float w = e[0] + e[1] + e[2] + e[3] + e[4] + e[5] + e[6];
    if (!edgeblk) {
#pragma unroll
      for (int i = 0; i < 10; ++i) {
        int rr = r0 + i;
        if (rr < BM) Cs[rr][10 + d] = w * (1.0f / 7.0f);
        if (i < 9) w += e[i + 7] - e[i];
      }
    } else {
#pragma unroll
      for (int i = 0; i < 10; ++i) {
        int rr = r0 + i;
        if (rr < BM) {
          long row = base + rr;
          long lo = row - 3; if (lo < 0) lo = 0;
          long hi = row + 4; if (hi > (long)N) hi = (long)N;
          long c = hi - lo;  if (c < 1) c = 1;
          Cs[rr][10 + d] = w / (float)c;
        }
        if (i < 9) w += e[i + 7] - e[i];
      }
    }
  }
  __syncthreads();

  // ---- MFMA phase: 4 waves x 2 row-tiles each ----
  // A frag (16x16x32): row = lane&15, k = ks*32 + kg*8 + e.
  short8 aHi[2][2], aLo[2][2];  // [rtl][ks]
#pragma unroll
  for (int rtl = 0; rtl < 2; ++rtl) {
    const int r = (wid * 2 + rtl) * 16 + arow;
    const float* crow = &Cs[r][0];
    const float4 qa = rtl ? qa1 : qa0;
    const float4 qb = rtl ? qb1 : qb0;
    U8 h0, l0, h1, l1;
    if (kg <= 1) {                 // k 0-15: embeddings from Cs
#pragma unroll
      for (int i = 0; i < 4; ++i) {
        float2 t = *(const float2*)(crow + kg * 8 + 2 * i);
        split_pair(t.x, t.y, h0.u[i], l0.u[i]);
      }
    } else if (kg == 2) {          // k16-19 Cs, k20-23 numeric
      float2 t0 = *(const float2*)(crow + 16);
      float2 t1 = *(const float2*)(crow + 18);
      split_pair(t0.x, t0.y, h0.u[0], l0.u[0]);
      split_pair(t1.x, t1.y, h0.u[1], l0.u[1]);
      split_pair(qa.x, qa.y, h0.u[2], l0.u[2]);
      split_pair(qa.z, qa.w, h0.u[3], l0.u[3]);
    } else {                       // kg==3: k24-31 numeric n4-11
      split_pair(qa.x, qa.y, h0.u[0], l0.u[0]);
      split_pair(qa.z, qa.w, h0.u[1], l0.u[1]);
      split_pair(qb.x, qb.y, h0.u[2], l0.u[2]);
      split_pair(qb.z, qb.w, h0.u[3], l0.u[3]);
    }
    if (kg == 0) {                 // ks1: k32-35 = n12-15, k36 = bias 1.0
      split_pair(qa.x, qa.y, h1.u[0], l1.u[0]);
      split_pair(qa.z, qa.w, h1.u[1], l1.u[1]);
      h1.u[2] = 0x00003F80u; l1.u[2] = 0u;   // bf16(1.0) in low half, pad 0
      h1.u[3] = 0u;          l1.u[3] = 0u;
    } else {
      h1.u[0] = h1.u[1] = h1.u[2] = h1.u[3] = 0u;
      l1.u[0] = l1.u[1] = l1.u[2] = l1.u[3] = 0u;
    }
    aHi[rtl][0] = h0.v; aLo[rtl][0] = l0.v;
    aHi[rtl][1] = h1.v; aLo[rtl][1] = l1.v;
  }

  float part[2][4] = {{0,0,0,0},{0,0,0,0}};
#pragma unroll
  for (int ct = 0; ct < 8; ++ct) {
    short8 bb[2][2];
#pragma unroll
    for (int term = 0; term < 2; ++term)
#pragma unroll
      for (int ks = 0; ks < 2; ++ks)
        bb[term][ks] = *(const short8*)(Bpack +
            (size_t)(((term * 8 + ct) * 2 + ks) * 64 + l) * 8);
    float w2c = W2s[ct * 16 + (l & 15)];
#pragma unroll
    for (int rtl = 0; rtl < 2; ++rtl) {
      f32x4 acc = {0.0f, 0.0f, 0.0f, 0.0f};
#pragma unroll
      for (int ks = 0; ks < 2; ++ks) {
        acc = __builtin_amdgcn_mfma_f32_16x16x32_bf16(aHi[rtl][ks], bb[0][ks], acc, 0, 0, 0);
        acc = __builtin_amdgcn_mfma_f32_16x16x32_bf16(aLo[rtl][ks], bb[0][ks], acc, 0, 0, 0);
        acc = __builtin_amdgcn_mfma_f32_16x16x32_bf16(aHi[rtl][ks], bb[1][ks], acc, 0, 0, 0);
      }
#pragma unroll
      for (int r = 0; r < 4; ++r) {
        float hv = fmaxf(acc[r], 0.0f);    // relu(h + b1) — b1 folded via bias slot
        part[rtl][r] += hv * w2c;          // partial W2 dot
      }
    }
  }
  // reduce the W2 dot across the 16 column-lanes
#pragma unroll
  for (int off = 1; off < 16; off <<= 1) {
#pragma unroll
    for (int rtl = 0; rtl < 2; ++rtl)
#pragma unroll
      for (int r = 0; r < 4; ++r)
        part[rtl][r] += __shfl_xor(part[rtl][r], off, 64);
  }
  if ((l & 15) < 4) {
    float b2v = b2[0];
#pragma unroll
    for (int rtl = 0; rtl < 2; ++rtl) {
      int rt = wid * 2 + rtl;
      long grow = base + rt * 16 + (l >> 4) * 4 + (l & 15);
      if (grow < (long)N) {
        float x = part[rtl][l & 15] + b2v;
        out[grow] = 1.0f / (1.0f + exp2f(x * -1.44269504f));
      }
    }
  }
}

extern "C" void kernel_launch(void* const* d_in, const int* in_sizes, int n_in,
                              void* d_out, int out_size, void* d_ws, size_t ws_size,
                              hipStream_t stream) {
  const int*   t1   = (const int*)d_in[0];
  const int*   t2   = (const int*)d_in[1];
  const float* numf = (const float*)d_in[2];
  const float* tab1 = (const float*)d_in[3];
  const float* tab2 = (const float*)d_in[4];
  const float* W1   = (const float*)d_in[5];
  const float* b1   = (const float*)d_in[6];
  const float* W2   = (const float*)d_in[7];
  const float* b2   = (const float*)d_in[8];
  float* out = (float*)d_out;
  const int N = in_sizes[0];
  short* Bpack = (short*)d_ws;   // 32 KB

  hipLaunchKernelGGL(prep_kernel, dim3(32), dim3(64), 0, stream, W1, b1, Bpack);
  int nblk = (N + BM - 1) / BM;
  hipLaunchKernelGGL(fused_kernel, dim3(nblk), dim3(256), 0, stream,
                     t1, t2, numf, tab1, tab2, Bpack, W2, b2, out, N);
}